// Round 1
// baseline (2013.274 us; speedup 1.0000x reference)
//
#include <hip/hip_runtime.h>

typedef __bf16 bf16x8 __attribute__((ext_vector_type(8)));
typedef __bf16 bf16x4 __attribute__((ext_vector_type(4)));
typedef float  f32x4  __attribute__((ext_vector_type(4)));

#define ATTN_EPS 1e-8f
#define K_SCALE  0.07216878364870322f   // 192^-0.5

// swizzled bf16 store: byte = row*strideB + ((col*2) ^ ((row&7)<<4))
__device__ __forceinline__ void st_swz(__bf16* buf, int strideB, int row, int col, float v) {
  *(__bf16*)((char*)buf + row * strideB + ((col * 2) ^ ((row & 7) << 4))) = (__bf16)v;
}

// A from swizzled LDS (rows = lane&15), B from global prepped [col][k] (contiguous k)
template <int KSTEPS>
__device__ __forceinline__ f32x4 mm16(const __bf16* a_lds, int astrideB,
                                      const __bf16* __restrict__ Bg, int ldb,
                                      int n0, int lane) {
  int arow = lane & 15, kgr = lane >> 4;
  const char* ab = (const char*)a_lds + arow * astrideB;
  int aswz = (arow & 7) << 4;
  const __bf16* bp = Bg + (n0 + arow) * ldb + kgr * 8;
  f32x4 acc = {0.f, 0.f, 0.f, 0.f};
#pragma unroll
  for (int ki = 0; ki < KSTEPS; ++ki) {
    bf16x8 a = *(const bf16x8*)(ab + ((ki * 64 + kgr * 16) ^ aswz));
    bf16x8 b = *(const bf16x8*)(bp + ki * 32);
    acc = __builtin_amdgcn_mfma_f32_16x16x32_bf16(a, b, acc, 0, 0, 0);
  }
  return acc;
}

// ---------------- prep: cast/transpose weights to bf16 ----------------
__global__ __launch_bounds__(256) void prep_kernel(
    const float* __restrict__ Wk, const float* __restrict__ Wv, const float* __restrict__ Wq,
    const float* __restrict__ wih, const float* __restrict__ whh,
    const float* __restrict__ w1, const float* __restrict__ w2,
    const float* __restrict__ p1, const float* __restrict__ p2,
    __bf16* __restrict__ WkvP, __bf16* __restrict__ WqP,
    __bf16* __restrict__ wihB, __bf16* __restrict__ whhB,
    __bf16* __restrict__ w1P, __bf16* __restrict__ w2P,
    __bf16* __restrict__ pr1P, __bf16* __restrict__ pr2P) {
  int i = blockIdx.x * 256 + threadIdx.x;
  if (i < 73728) {  // WkvP [384][192], SCALE folded into k half
    int col = i / 192, c = i - col * 192;
    float v = (col < 192) ? Wk[c * 192 + col] * K_SCALE : Wv[c * 192 + (col - 192)];
    WkvP[i] = (__bf16)v; return;
  }
  i -= 73728;
  if (i < 36864) { int col = i / 192, c = i - col * 192; WqP[i] = (__bf16)Wq[c * 192 + col]; return; }
  i -= 36864;
  if (i < 110592) { wihB[i] = (__bf16)wih[i]; return; }
  i -= 110592;
  if (i < 110592) { whhB[i] = (__bf16)whh[i]; return; }
  i -= 110592;
  if (i < 147456) { int o = i / 192, c = i - o * 192; w1P[i] = (__bf16)w1[c * 768 + o]; return; }
  i -= 147456;
  if (i < 147456) { int o = i / 768, c = i - o * 768; w2P[i] = (__bf16)w2[c * 192 + o]; return; }
  i -= 147456;
  if (i < 36864) { int o = i / 192, c = i - o * 192; pr1P[i] = (__bf16)p1[c * 192 + o]; return; }
  i -= 36864;
  { int o = i / 192, c = i - o * 192; pr2P[i] = (__bf16)p2[c * 192 + o]; }
}

// ---------------- phase 1: LN(inputs) @ [Wk*SCALE | Wv] -> k (row-major), v (transposed) ----------------
__global__ __launch_bounds__(256) void p1_kernel(
    const float* __restrict__ x_in, const float* __restrict__ lng, const float* __restrict__ lnb,
    const __bf16* __restrict__ Wkv, __bf16* __restrict__ k_all, __bf16* __restrict__ v_all) {
  __shared__ __attribute__((aligned(16))) char pool[64 * 200 * 4];   // xs f32 [64][200]; later kst|vst
  __shared__ __attribute__((aligned(16))) __bf16 xh[64 * 192];       // swizzled LN output
  __shared__ float gsh[192], bsh[192];
  float* xs = (float*)pool;
  __bf16* kst = (__bf16*)pool;            // [64][192]
  __bf16* vst = (__bf16*)(pool + 24576);  // [192][64]

  const int tid = threadIdx.x;
  const int blk = blockIdx.x;
  const long Rbase = (long)blk * 64;
  if (tid < 192) { gsh[tid] = lng[tid]; bsh[tid] = lnb[tid]; }

  const float* gxp = x_in + Rbase * 192;
  for (int i = tid; i < 64 * 48; i += 256) {         // coalesced global -> LDS (padded rows)
    int row = i / 48, c4 = i - row * 48;
    float4 v = *(const float4*)(gxp + row * 192 + c4 * 4);
    float* d = xs + row * 200 + c4 * 4;
    d[0] = v.x; d[1] = v.y; d[2] = v.z; d[3] = v.w;
  }
  __syncthreads();

  const int r = tid >> 2, coff = (tid & 3) * 48;     // 4 threads per row
  float xr[48];
  const float* src = xs + r * 200 + coff;
#pragma unroll
  for (int j = 0; j < 48; j++) xr[j] = src[j];
  float s = 0.f, sq = 0.f;
#pragma unroll
  for (int j = 0; j < 48; j++) { s += xr[j]; sq += xr[j] * xr[j]; }
  s += __shfl_xor(s, 1, 64);  s += __shfl_xor(s, 2, 64);
  sq += __shfl_xor(sq, 1, 64); sq += __shfl_xor(sq, 2, 64);
  float mu = s * (1.f / 192.f);
  float var = sq * (1.f / 192.f) - mu * mu;
  float rs = rsqrtf(var + 1e-5f);
  {
    char* xrow = (char*)xh + r * 384;
    int swz = (r & 7) << 4;
#pragma unroll
    for (int j = 0; j < 6; j++) {
      bf16x8 o;
#pragma unroll
      for (int e = 0; e < 8; e++) {
        int c = coff + j * 8 + e;
        o[e] = (__bf16)((xr[j * 8 + e] - mu) * rs * gsh[c] + bsh[c]);
      }
      *(bf16x8*)(xrow + (((coff + j * 8) * 2) ^ swz)) = o;
    }
  }
  __syncthreads();

  const int w = tid >> 6, lane = tid & 63;
  const int arow = lane & 15, kgr = lane >> 4;
  const int m0 = w * 16;
  const char* ab = (const char*)xh + (m0 + arow) * 384;
  const int aswz = (arow & 7) << 4;

  for (int nt = 0; nt < 12; nt++) {                  // k columns 0..191
    int col = nt * 16 + arow;
    const __bf16* bp = Wkv + col * 192 + kgr * 8;
    f32x4 acc = {0.f, 0.f, 0.f, 0.f};
#pragma unroll
    for (int ki = 0; ki < 6; ki++) {
      bf16x8 a = *(const bf16x8*)(ab + ((ki * 64 + kgr * 16) ^ aswz));
      bf16x8 b = *(const bf16x8*)(bp + ki * 32);
      acc = __builtin_amdgcn_mfma_f32_16x16x32_bf16(a, b, acc, 0, 0, 0);
    }
#pragma unroll
    for (int rr = 0; rr < 4; rr++) kst[(m0 + kgr * 4 + rr) * 192 + col] = (__bf16)acc[rr];
  }
  for (int nt = 0; nt < 12; nt++) {                  // v columns, transposed staging
    int dcol = nt * 16 + arow;
    const __bf16* bp = Wkv + (192 + dcol) * 192 + kgr * 8;
    f32x4 acc = {0.f, 0.f, 0.f, 0.f};
#pragma unroll
    for (int ki = 0; ki < 6; ki++) {
      bf16x8 a = *(const bf16x8*)(ab + ((ki * 64 + kgr * 16) ^ aswz));
      bf16x8 b = *(const bf16x8*)(bp + ki * 32);
      acc = __builtin_amdgcn_mfma_f32_16x16x32_bf16(a, b, acc, 0, 0, 0);
    }
    bf16x4 o4;
#pragma unroll
    for (int rr = 0; rr < 4; rr++) o4[rr] = (__bf16)acc[rr];
    *(bf16x4*)(&vst[dcol * 64 + m0 + kgr * 4]) = o4;
  }
  __syncthreads();

  {  // k: 64 rows * 192 = contiguous 24576 B
    const uint4* s4 = (const uint4*)kst;
    uint4* d4 = (uint4*)(k_all + Rbase * 192);
    for (int i = tid; i < 1536; i += 256) d4[i] = s4[i];
  }
  {  // v transposed: [192][64] -> v_all[bt][d][n0g..n0g+63]
    int bt = blk >> 2;
    int n0g = (blk & 3) * 64;
    __bf16* vout = v_all + (long)bt * 49152 + n0g;
    for (int i = tid; i < 1536; i += 256) {
      int d = i >> 3, cc = i & 7;
      *(uint4*)((char*)(vout + d * 256) + cc * 16) =
          *(const uint4*)((const char*)vst + d * 128 + cc * 16);
    }
  }
}

// ---------------- phase 2: persistent block per batch, full scan ----------------
__global__ __launch_bounds__(1024) void p2_kernel(
    const __bf16* __restrict__ k_all, const __bf16* __restrict__ v_all,
    const __bf16* __restrict__ WqP, const __bf16* __restrict__ wihB, const __bf16* __restrict__ whhB,
    const __bf16* __restrict__ w1P, const __bf16* __restrict__ w2P,
    const __bf16* __restrict__ pr1P, const __bf16* __restrict__ pr2P,
    const float* __restrict__ noise, const float* __restrict__ mu_p, const float* __restrict__ lsig,
    const float* __restrict__ lnsg, const float* __restrict__ lnsb,
    const float* __restrict__ lnfg, const float* __restrict__ lnfb,
    const float* __restrict__ bih, const float* __restrict__ bhh,
    const float* __restrict__ b1p, const float* __restrict__ b2p,
    const float* __restrict__ prb1, const float* __restrict__ prb2,
    float* __restrict__ out) {
  __shared__ __attribute__((aligned(16))) float slots[8 * 192];
  __shared__ __attribute__((aligned(16))) __bf16 slots_bf[16 * 192];
  __shared__ __attribute__((aligned(16))) __bf16 ln_bf[16 * 192];
  __shared__ __attribute__((aligned(16))) __bf16 q_bf[16 * 192];
  __shared__ __attribute__((aligned(16))) __bf16 upd_bf[16 * 192];
  __shared__ __attribute__((aligned(16))) __bf16 attnT[16 * 256];
  __shared__ __attribute__((aligned(16))) __bf16 a_bf[16 * 768];
  __shared__ float gx[8 * 577];
  __shared__ float gh[8 * 577];
  __shared__ float colsum[8];
  __shared__ float Lsg[192], Lsb[192], Lfg[192], Lfb[192];
  __shared__ float Bih[576], Bhh[576], B1s[768], B2s[192], Pb1s[192], Pb2s[192];

  const int tid = threadIdx.x;
  const int w = tid >> 6, lane = tid & 63;
  const int b = blockIdx.x;
  const int kgr = lane >> 4, arow = lane & 15;

  for (int i = tid; i < 192; i += 1024) {
    Lsg[i] = lnsg[i]; Lsb[i] = lnsb[i]; Lfg[i] = lnfg[i]; Lfb[i] = lnfb[i];
    B2s[i] = b2p[i]; Pb1s[i] = prb1[i]; Pb2s[i] = prb2[i];
  }
  for (int i = tid; i < 576; i += 1024) { Bih[i] = bih[i]; Bhh[i] = bhh[i]; }
  for (int i = tid; i < 768; i += 1024) B1s[i] = b1p[i];
  for (int i = tid; i < 16 * 192; i += 1024) {
    slots_bf[i] = (__bf16)0.f; ln_bf[i] = (__bf16)0.f; q_bf[i] = (__bf16)0.f; upd_bf[i] = (__bf16)0.f;
  }
  for (int i = tid; i < 16 * 256; i += 1024) attnT[i] = (__bf16)0.f;
  for (int i = tid; i < 16 * 768; i += 1024) a_bf[i] = (__bf16)0.f;
  __syncthreads();
  for (int i = tid; i < 1536; i += 1024) {           // slots0 = mu + exp(lsig)*noise
    int s = i / 192, d = i - s * 192;
    float v = mu_p[d] + expf(lsig[d]) * noise[(b * 8 + s) * 192 + d];
    slots[i] = v;
    st_swz(slots_bf, 384, s, d, v);
  }
  __syncthreads();

  float* out_slots = out;
  float* out_dots = out + 786432;

  for (int t = 0; t < 16; ++t) {
    const __bf16* kb = k_all + (long)(b * 16 + t) * 49152;  // [256][192]
    const __bf16* vb = v_all + (long)(b * 16 + t) * 49152;  // [192][256]
    for (int it = 0; it < 3; ++it) {
      // 1) LN(slots) -> ln_bf ; zero colsum
      if (tid < 8) colsum[tid] = 0.f;
      if (w < 8) {
        int s = w;
        float v0 = slots[s * 192 + lane], v1 = slots[s * 192 + 64 + lane], v2 = slots[s * 192 + 128 + lane];
        float sm = v0 + v1 + v2, sq = v0 * v0 + v1 * v1 + v2 * v2;
#pragma unroll
        for (int m = 1; m < 64; m <<= 1) { sm += __shfl_xor(sm, m, 64); sq += __shfl_xor(sq, m, 64); }
        float mu = sm * (1.f / 192.f);
        float var = sq * (1.f / 192.f) - mu * mu;
        float rs = rsqrtf(var + 1e-5f);
        st_swz(ln_bf, 384, s, lane,       (v0 - mu) * rs * Lsg[lane]       + Lsb[lane]);
        st_swz(ln_bf, 384, s, lane + 64,  (v1 - mu) * rs * Lsg[lane + 64]  + Lsb[lane + 64]);
        st_swz(ln_bf, 384, s, lane + 128, (v2 - mu) * rs * Lsg[lane + 128] + Lsb[lane + 128]);
      }
      __syncthreads();
      // 2) q = ln @ Wq
      if (w < 12) {
        f32x4 acc = mm16<6>(ln_bf, 384, WqP, 192, w * 16, lane);
        if (kgr < 2) {
          int col = w * 16 + arow;
#pragma unroll
          for (int rr = 0; rr < 4; rr++) st_swz(q_bf, 384, kgr * 4 + rr, col, acc[rr]);
        }
      }
      __syncthreads();
      // 3) dots^T = q @ k^T, softmax over s, stash attn^T (+eps) and colsum
      {
        f32x4 acc = mm16<6>(q_bf, 384, kb, 192, w * 16, lane);
        float m4 = fmaxf(fmaxf(acc[0], acc[1]), fmaxf(acc[2], acc[3]));
        float m8 = fmaxf(m4, __shfl_xor(m4, 16, 64));
        float p0 = __expf(acc[0] - m8), p1 = __expf(acc[1] - m8);
        float p2 = __expf(acc[2] - m8), p3 = __expf(acc[3] - m8);
        float s4 = p0 + p1 + p2 + p3;
        float den = s4 + __shfl_xor(s4, 16, 64);
        float rden = 1.f / den;
        if (kgr < 2) {
          int n = w * 16 + arow;
          float a0 = p0 * rden, a1 = p1 * rden, a2 = p2 * rden, a3 = p3 * rden;
          if (it == 2) {
            float4 o4 = make_float4(a0, a1, a2, a3);
            *(float4*)(out_dots + ((long)(b * 16 + t) * 256 + n) * 8 + kgr * 4) = o4;
          }
          __bf16 e0 = (__bf16)(a0 + ATTN_EPS), e1 = (__bf16)(a1 + ATTN_EPS);
          __bf16 e2 = (__bf16)(a2 + ATTN_EPS), e3 = (__bf16)(a3 + ATTN_EPS);
          int srow = kgr * 4;
          char* base = (char*)attnT;
          *(__bf16*)(base + (srow + 0) * 512 + ((n * 2) ^ (((srow + 0) & 7) << 4))) = e0;
          *(__bf16*)(base + (srow + 1) * 512 + ((n * 2) ^ (((srow + 1) & 7) << 4))) = e1;
          *(__bf16*)(base + (srow + 2) * 512 + ((n * 2) ^ (((srow + 2) & 7) << 4))) = e2;
          *(__bf16*)(base + (srow + 3) * 512 + ((n * 2) ^ (((srow + 3) & 7) << 4))) = e3;
          float c0 = (float)e0, c1 = (float)e1, c2 = (float)e2, c3 = (float)e3;
#pragma unroll
          for (int m = 1; m < 16; m <<= 1) {
            c0 += __shfl_xor(c0, m, 64); c1 += __shfl_xor(c1, m, 64);
            c2 += __shfl_xor(c2, m, 64); c3 += __shfl_xor(c3, m, 64);
          }
          if (arow == 0) {
            atomicAdd(&colsum[srow + 0], c0); atomicAdd(&colsum[srow + 1], c1);
            atomicAdd(&colsum[srow + 2], c2); atomicAdd(&colsum[srow + 3], c3);
          }
        }
      }
      __syncthreads();
      // 4) updates = attn^T @ v / colsum
      if (w < 12) {
        f32x4 acc = mm16<8>(attnT, 512, vb, 256, w * 16, lane);
        if (kgr < 2) {
          int col = w * 16 + arow;
#pragma unroll
          for (int rr = 0; rr < 4; rr++) {
            int s = kgr * 4 + rr;
            st_swz(upd_bf, 384, s, col, acc[rr] / colsum[s]);
          }
        }
      }
      __syncthreads();
      // 5) GRU matmuls: gx = upd @ wih^T, gh = slots @ whh^T
      for (int job = w; job < 72; job += 16) {
        bool isx = job < 36;
        int nt = isx ? job : job - 36;
        f32x4 acc = mm16<6>(isx ? upd_bf : slots_bf, 384, isx ? wihB : whhB, 192, nt * 16, lane);
        if (kgr < 2) {
          int col = nt * 16 + arow;
          float* dst = isx ? gx : gh;
#pragma unroll
          for (int rr = 0; rr < 4; rr++) dst[(kgr * 4 + rr) * 577 + col] = acc[rr];
        }
      }
      __syncthreads();
      // 6) gates
      for (int i = tid; i < 1536; i += 1024) {
        int s = i / 192, d = i - s * 192;
        float xr_ = gx[s * 577 + d]       + Bih[d];
        float xz_ = gx[s * 577 + 192 + d] + Bih[192 + d];
        float xn_ = gx[s * 577 + 384 + d] + Bih[384 + d];
        float hr_ = gh[s * 577 + d]       + Bhh[d];
        float hz_ = gh[s * 577 + 192 + d] + Bhh[192 + d];
        float hn_ = gh[s * 577 + 384 + d] + Bhh[384 + d];
        float rg = 1.f / (1.f + __expf(-(xr_ + hr_)));
        float zg = 1.f / (1.f + __expf(-(xz_ + hz_)));
        float ng = tanhf(xn_ + rg * hn_);
        float hv = slots[i];
        float nh = (1.f - zg) * ng + zg * hv;
        slots[i] = nh;
        st_swz(slots_bf, 384, s, d, nh);
      }
      __syncthreads();
      // 7) MLP residual (it < 2)
      if (it < 2) {
        if (w < 8) {
          int s = w;
          float v0 = slots[s * 192 + lane], v1 = slots[s * 192 + 64 + lane], v2 = slots[s * 192 + 128 + lane];
          float sm = v0 + v1 + v2, sq = v0 * v0 + v1 * v1 + v2 * v2;
#pragma unroll
          for (int m = 1; m < 64; m <<= 1) { sm += __shfl_xor(sm, m, 64); sq += __shfl_xor(sq, m, 64); }
          float mu = sm * (1.f / 192.f);
          float var = sq * (1.f / 192.f) - mu * mu;
          float rs = rsqrtf(var + 1e-5f);
          st_swz(ln_bf, 384, s, lane,       (v0 - mu) * rs * Lfg[lane]       + Lfb[lane]);
          st_swz(ln_bf, 384, s, lane + 64,  (v1 - mu) * rs * Lfg[lane + 64]  + Lfb[lane + 64]);
          st_swz(ln_bf, 384, s, lane + 128, (v2 - mu) * rs * Lfg[lane + 128] + Lfb[lane + 128]);
        }
        __syncthreads();
        for (int job = w; job < 48; job += 16) {
          f32x4 acc = mm16<6>(ln_bf, 384, w1P, 192, job * 16, lane);
          if (kgr < 2) {
            int col = job * 16 + arow;
#pragma unroll
            for (int rr = 0; rr < 4; rr++)
              st_swz(a_bf, 1536, kgr * 4 + rr, col, fmaxf(acc[rr] + B1s[col], 0.f));
          }
        }
        __syncthreads();
        if (w < 12) {
          f32x4 acc = mm16<24>(a_bf, 1536, w2P, 768, w * 16, lane);
          if (kgr < 2) {
            int col = w * 16 + arow;
#pragma unroll
            for (int rr = 0; rr < 4; rr++) {
              int s = kgr * 4 + rr;
              float nv = slots[s * 192 + col] + acc[rr] + B2s[col];
              slots[s * 192 + col] = nv;
              st_swz(slots_bf, 384, s, col, nv);
            }
          }
        }
        __syncthreads();
      }
    }  // it
    // out_slots (pre-prior)
    for (int i = tid; i < 384; i += 1024)
      *(float4*)(out_slots + (long)(b * 16 + t) * 1536 + i * 4) = *(const float4*)(&slots[i * 4]);
    // prior MLP -> carried slots
    if (w < 12) {
      f32x4 acc = mm16<6>(slots_bf, 384, pr1P, 192, w * 16, lane);
      if (kgr < 2) {
        int col = w * 16 + arow;
#pragma unroll
        for (int rr = 0; rr < 4; rr++)
          st_swz(ln_bf, 384, kgr * 4 + rr, col, fmaxf(acc[rr] + Pb1s[col], 0.f));
      }
    }
    __syncthreads();
    if (w < 12) {
      f32x4 acc = mm16<6>(ln_bf, 384, pr2P, 192, w * 16, lane);
      if (kgr < 2) {
        int col = w * 16 + arow;
#pragma unroll
        for (int rr = 0; rr < 4; rr++) {
          int s = kgr * 4 + rr;
          float nv = acc[rr] + Pb2s[col];
          slots[s * 192 + col] = nv;
          st_swz(slots_bf, 384, s, col, nv);
        }
      }
    }
    __syncthreads();
  }  // t
}

extern "C" void kernel_launch(void* const* d_in, const int* in_sizes, int n_in,
                              void* d_out, int out_size, void* d_ws, size_t ws_size,
                              hipStream_t stream) {
  const float* inputs = (const float*)d_in[0];
  const float* noise  = (const float*)d_in[1];
  const float* mu     = (const float*)d_in[2];
  const float* lsig   = (const float*)d_in[3];
  const float* ln_in_g = (const float*)d_in[4];
  const float* ln_in_b = (const float*)d_in[5];
  const float* Wk = (const float*)d_in[6];
  const float* Wv = (const float*)d_in[7];
  const float* Wq = (const float*)d_in[8];
  const float* lnsg = (const float*)d_in[9];
  const float* lnsb = (const float*)d_in[10];
  const float* wih = (const float*)d_in[11];
  const float* whh = (const float*)d_in[12];
  const float* bih = (const float*)d_in[13];
  const float* bhh = (const float*)d_in[14];
  const float* lnfg = (const float*)d_in[15];
  const float* lnfb = (const float*)d_in[16];
  const float* w1 = (const float*)d_in[17];
  const float* b1 = (const float*)d_in[18];
  const float* w2 = (const float*)d_in[19];
  const float* b2 = (const float*)d_in[20];
  const float* pw1 = (const float*)d_in[21];
  const float* pb1 = (const float*)d_in[22];
  const float* pw2 = (const float*)d_in[23];
  const float* pb2 = (const float*)d_in[24];

  char* ws = (char*)d_ws;
  __bf16* WkvP = (__bf16*)(ws + 0);
  __bf16* WqP  = (__bf16*)(ws + 147456);
  __bf16* wihB = (__bf16*)(ws + 221184);
  __bf16* whhB = (__bf16*)(ws + 442368);
  __bf16* w1P  = (__bf16*)(ws + 663552);
  __bf16* w2P  = (__bf16*)(ws + 958464);
  __bf16* pr1P = (__bf16*)(ws + 1253376);
  __bf16* pr2P = (__bf16*)(ws + 1327104);
  __bf16* k_all = (__bf16*)(ws + 1400832);
  __bf16* v_all = (__bf16*)(ws + 51732480);
  // total ws usage: 102064128 bytes

  prep_kernel<<<2736, 256, 0, stream>>>(Wk, Wv, Wq, wih, whh, w1, w2, pw1, pw2,
                                        WkvP, WqP, wihB, whhB, w1P, w2P, pr1P, pr2P);
  p1_kernel<<<2048, 256, 0, stream>>>(inputs, ln_in_g, ln_in_b, WkvP, k_all, v_all);
  p2_kernel<<<32, 1024, 0, stream>>>(k_all, v_all, WqP, wihB, whhB, w1P, w2P, pr1P, pr2P,
                                     noise, mu, lsig, lnsg, lnsb, lnfg, lnfb,
                                     bih, bhh, b1, b2, pb1, pb2, (float*)d_out);
}